// Round 2
// baseline (412.806 us; speedup 1.0000x reference)
//
#include <hip/hip_runtime.h>
#include <hip/hip_bf16.h>

#define N_NODES 50000
#define N_EDGES 800000
#define D 64

// ---------------------------------------------------------------------------
// Workspace layout (ints are 4B, floats 4B):
//   out_deg  : int[N_NODES]     (zeroed by memset)
//   in_deg   : int[N_NODES]     (zeroed by memset)
//   row_ptr  : int[N_NODES]     (written by scan)
//   cursor   : int[N_NODES]     (written by scan, mutated by fill)
//   edge_src : int[N_EDGES]     (written by fill)
//   y        : float[N_NODES*D] (written by transform)
// ---------------------------------------------------------------------------
#define OUTDEG_OFF   0
#define INDEG_OFF    (OUTDEG_OFF + N_NODES * 4)
#define ROWPTR_OFF   (INDEG_OFF + N_NODES * 4)
#define CURSOR_OFF   (ROWPTR_OFF + N_NODES * 4)
#define EDGESRC_OFF  (CURSOR_OFF + N_NODES * 4)
#define Y_OFF        (EDGESRC_OFF + N_EDGES * 4)
#define ZERO_BYTES   (2 * N_NODES * 4)   // only the two degree histograms

// 1 thread per edge: histogram both degree arrays.
__global__ void degree_kernel(const int* __restrict__ src,
                              const int* __restrict__ dst,
                              int* __restrict__ out_deg,
                              int* __restrict__ in_deg) {
    int e = blockIdx.x * blockDim.x + threadIdx.x;
    if (e < N_EDGES) {
        atomicAdd(&out_deg[src[e]], 1);
        atomicAdd(&in_deg[dst[e]], 1);
    }
}

// Single-block exclusive scan of in_deg -> row_ptr and cursor (identical copies).
// 1024 threads, each owns a contiguous chunk of ceil(N/1024)=49 elements.
#define SCAN_T 1024
#define SCAN_CHUNK ((N_NODES + SCAN_T - 1) / SCAN_T)
__global__ void scan_kernel(const int* __restrict__ in_deg,
                            int* __restrict__ row_ptr,
                            int* __restrict__ cursor) {
    __shared__ int sums[SCAN_T];
    int t = threadIdx.x;
    int begin = t * SCAN_CHUNK;
    int end = min(begin + SCAN_CHUNK, N_NODES);
    int s = 0;
    for (int i = begin; i < end; i++) s += in_deg[i];
    sums[t] = s;
    __syncthreads();
    // Hillis-Steele inclusive scan over the 1024 thread-sums.
    for (int off = 1; off < SCAN_T; off <<= 1) {
        int v = (t >= off) ? sums[t - off] : 0;
        __syncthreads();
        sums[t] += v;
        __syncthreads();
    }
    int run = sums[t] - s;  // exclusive base for this thread's chunk
    for (int i = begin; i < end; i++) {
        row_ptr[i] = run;
        cursor[i] = run;
        run += in_deg[i];
    }
}

// Bucket edges by dst: edge_src[pos] = src.
__global__ void fill_kernel(const int* __restrict__ src,
                            const int* __restrict__ dst,
                            int* __restrict__ cursor,
                            int* __restrict__ edge_src) {
    int e = blockIdx.x * blockDim.x + threadIdx.x;
    if (e < N_EDGES) {
        int pos = atomicAdd(&cursor[dst[e]], 1);
        edge_src[pos] = src[e];
    }
}

// y[n][j] = rsqrt(max(out_deg[n],1)) * sum_k x[n][k] * W[k][j]
// Block = 256 threads = 4 nodes x 64 output columns. W staged in LDS.
__global__ void transform_kernel(const float* __restrict__ x,
                                 const int* __restrict__ out_deg,
                                 const float* __restrict__ W,
                                 float* __restrict__ y) {
    __shared__ float Ws[D * D];
    for (int i = threadIdx.x; i < D * D; i += blockDim.x) Ws[i] = W[i];
    __syncthreads();

    int j = threadIdx.x & 63;
    int n = blockIdx.x * (blockDim.x >> 6) + (threadIdx.x >> 6);
    if (n < N_NODES) {
        float scale = rsqrtf(fmaxf((float)out_deg[n], 1.0f));
        const float* xrow = x + (size_t)n * D;
        float sum = 0.0f;
#pragma unroll
        for (int k = 0; k < D; k++) {
            sum = fmaf(xrow[k], Ws[k * D + j], sum);
        }
        y[n * D + j] = sum * scale;
    }
}

// out[n][j] = rsqrt(max(in_deg[n],1)) * sum_{e in bucket(n)} y[edge_src[e]][j] + b[j]
// One wave per node, lane = feature. Deterministic single write per output element.
__global__ void gather_kernel(const float* __restrict__ y,
                              const int* __restrict__ row_ptr,
                              const int* __restrict__ cursor,
                              const int* __restrict__ edge_src,
                              const float* __restrict__ b,
                              float* __restrict__ out) {
    int lane = threadIdx.x & 63;
    int n = blockIdx.x * (blockDim.x >> 6) + (threadIdx.x >> 6);
    if (n >= N_NODES) return;
    int beg = row_ptr[n];
    int end = cursor[n];  // after fill, cursor[n] == row_ptr[n] + in_deg[n]
    float sum = 0.0f;
    for (int i = beg; i < end; i++) {
        int s = edge_src[i];
        sum += y[s * D + lane];
    }
    float nd = rsqrtf(fmaxf((float)(end - beg), 1.0f));
    out[n * D + lane] = nd * sum + b[lane];
}

extern "C" void kernel_launch(void* const* d_in, const int* in_sizes, int n_in,
                              void* d_out, int out_size, void* d_ws, size_t ws_size,
                              hipStream_t stream) {
    const float* x   = (const float*)d_in[0];
    const int*   src = (const int*)d_in[1];
    const int*   dst = (const int*)d_in[2];
    const float* W   = (const float*)d_in[3];
    const float* b   = (const float*)d_in[4];
    float* out = (float*)d_out;

    char* ws = (char*)d_ws;
    int*   outdeg   = (int*)(ws + OUTDEG_OFF);
    int*   indeg    = (int*)(ws + INDEG_OFF);
    int*   row_ptr  = (int*)(ws + ROWPTR_OFF);
    int*   cursor   = (int*)(ws + CURSOR_OFF);
    int*   edge_src = (int*)(ws + EDGESRC_OFF);
    float* y        = (float*)(ws + Y_OFF);

    hipMemsetAsync(d_ws, 0, ZERO_BYTES, stream);

    {
        int threads = 256;
        int blocks = (N_EDGES + threads - 1) / threads;
        degree_kernel<<<blocks, threads, 0, stream>>>(src, dst, outdeg, indeg);
    }
    scan_kernel<<<1, SCAN_T, 0, stream>>>(indeg, row_ptr, cursor);
    {
        int threads = 256;
        int blocks = (N_EDGES + threads - 1) / threads;
        fill_kernel<<<blocks, threads, 0, stream>>>(src, dst, cursor, edge_src);
    }
    {
        int threads = 256;  // 4 nodes per block
        int blocks = (N_NODES + 3) / 4;
        transform_kernel<<<blocks, threads, 0, stream>>>(x, outdeg, W, y);
    }
    {
        int threads = 256;  // 4 nodes (waves) per block
        int blocks = (N_NODES + 3) / 4;
        gather_kernel<<<blocks, threads, 0, stream>>>(y, row_ptr, cursor, edge_src, b, out);
    }
}